// Round 3
// baseline (337.794 us; speedup 1.0000x reference)
//
#include <hip/hip_runtime.h>
#include <math.h>

#define BB 128
#define TT 2048
#define OO 128
#define EE 512
#define LL 34
#define XDIM 640       // O+E
#define SUBCH 64       // flash partials per batch row
#define SUB_LEN 32     // rows per wave

__device__ __forceinline__ float sigmoidf_(float x) { return 1.0f / (1.0f + __expf(-x)); }

// ---------------- K1: LSTM cell, fused GEMM + activation.
__global__ __launch_bounds__(256) void lstm_kernel(
    const float* __restrict__ y1, const float* __restrict__ c1,
    const float* __restrict__ sh1, const float* __restrict__ sc1,
    const float* __restrict__ Wih, const float* __restrict__ bih,
    const float* __restrict__ Whh, const float* __restrict__ bhh,
    float* __restrict__ out_sh, float* __restrict__ out_sc)
{
    __shared__ float xs[4][768];          // per batch row: [y1(512)|c1(128)|sh1(128)]
    __shared__ float gbuf[4][4][16];      // [gate][bi][o_local]
    const int tid = threadIdx.x;
    const int otile = blockIdx.x;
    const int qb = blockIdx.y * 4;

    for (int idx = tid; idx < 4 * 768; idx += 256) {
        int bi = idx / 768, k = idx - bi * 768;
        int b = qb + bi;
        float v;
        if (k < 512)      v = y1[b * EE + k];
        else if (k < 640) v = c1[b * OO + (k - 512)];
        else              v = sh1[b * OO + (k - 640)];
        xs[bi][k] = v;
    }
    __syncthreads();

    const int g = tid >> 6, l = tid & 63;   // wave g = gate g
    #pragma unroll 2
    for (int i = 0; i < 16; ++i) {
        const int row = g * 128 + otile * 16 + i;
        const float* wr = Wih + (size_t)row * XDIM;
        float a0 = 0.f, a1 = 0.f, a2 = 0.f, a3 = 0.f;
        #pragma unroll
        for (int j = 0; j < 10; ++j) {
            float wv = wr[l + 64 * j];
            a0 += wv * xs[0][l + 64 * j];
            a1 += wv * xs[1][l + 64 * j];
            a2 += wv * xs[2][l + 64 * j];
            a3 += wv * xs[3][l + 64 * j];
        }
        const float* wh = Whh + (size_t)row * OO;
        #pragma unroll
        for (int j = 0; j < 2; ++j) {
            float wv = wh[l + 64 * j];
            a0 += wv * xs[0][640 + l + 64 * j];
            a1 += wv * xs[1][640 + l + 64 * j];
            a2 += wv * xs[2][640 + l + 64 * j];
            a3 += wv * xs[3][640 + l + 64 * j];
        }
        #pragma unroll
        for (int off = 32; off >= 1; off >>= 1) {
            a0 += __shfl_xor(a0, off);
            a1 += __shfl_xor(a1, off);
            a2 += __shfl_xor(a2, off);
            a3 += __shfl_xor(a3, off);
        }
        if (l == 0) {
            float bb = bih[row] + bhh[row];
            gbuf[g][0][i] = a0 + bb;
            gbuf[g][1][i] = a1 + bb;
            gbuf[g][2][i] = a2 + bb;
            gbuf[g][3][i] = a3 + bb;
        }
    }
    __syncthreads();

    if (tid < 64) {
        const int bi = tid >> 4, ol = tid & 15;
        const int b = qb + bi, o = otile * 16 + ol;
        float gi = gbuf[0][bi][ol], gf = gbuf[1][bi][ol];
        float gg = gbuf[2][bi][ol], go = gbuf[3][bi][ol];
        float sc = sigmoidf_(gf) * sc1[b * OO + o] + sigmoidf_(gi) * tanhf(gg);
        float sh = sigmoidf_(go) * tanhf(sc);
        out_sc[b * OO + o] = sc;
        out_sh[b * OO + o] = sh;
    }
}

// ---------------- K2: barrier-free flash attention partials, deep-MLP version.
// Lane layout: p=lane>>5 (row parity), q=lane&31 (col quad) -> every float4
// load instruction covers exactly 1KB contiguous (2 rows of 512B).
// Register staging: all 16 hk float4s held in named regs (static indexing),
// hv loads issued BEFORE the shuffle-reduce chain so their HBM latency hides
// under the softmax reduction. No __syncthreads anywhere.
__global__ __launch_bounds__(256, 2) void attn_kernel(
    const float* __restrict__ hk, const float* __restrict__ hv,
    const float* __restrict__ mask, const float* __restrict__ sc,
    float* __restrict__ ws_c, float2* __restrict__ pbuf)
{
    const int b = blockIdx.y;
    const int tid = threadIdx.x;
    const int wave = tid >> 6, lane = tid & 63;
    const int subchunk = blockIdx.x * 4 + wave;     // 0..63
    const int p = lane >> 5, q = lane & 31;
    const int r0 = subchunk * SUB_LEN;

    const float4 scq = *(const float4*)(sc + b * OO + q * 4);
    const float* mbase = mask + (size_t)b * TT + r0 + p;
    const float* kbase = hk + ((size_t)b * TT + r0 + p) * OO + q * 4;
    const float* vbase = hv + ((size_t)b * TT + r0 + p) * OO + q * 4;

    // masks for my parity's 16 rows (issued first, tiny broadcast loads)
    float mk[16];
    #pragma unroll
    for (int j = 0; j < 16; ++j) mk[j] = mbase[2 * j];

    // ---- stage ALL hk tiles into registers: 16 x 1KB contiguous loads in flight
    float4 kv[16];
    #pragma unroll
    for (int j = 0; j < 16; ++j)
        kv[j] = *(const float4*)(kbase + (size_t)(2 * j) * OO);

    // per-lane partial dot (frees kv registers for vv reuse)
    float d[16];
    #pragma unroll
    for (int j = 0; j < 16; ++j)
        d[j] = kv[j].x * scq.x + kv[j].y * scq.y + kv[j].z * scq.z + kv[j].w * scq.w;

    // ---- issue ALL hv loads now; latency hides under the reduce below
    float4 vv[16];
    #pragma unroll
    for (int j = 0; j < 16; ++j)
        vv[j] = *(const float4*)(vbase + (size_t)(2 * j) * OO);

    // ---- softmax reduce: sum d[j] over the 32 lanes of this parity half
    #pragma unroll
    for (int j = 0; j < 16; ++j) {
        d[j] += __shfl_xor(d[j], 1);
        d[j] += __shfl_xor(d[j], 2);
        d[j] += __shfl_xor(d[j], 4);
        d[j] += __shfl_xor(d[j], 8);
        d[j] += __shfl_xor(d[j], 16);
    }
    float m = -INFINITY;
    #pragma unroll
    for (int j = 0; j < 16; ++j) if (mk[j] != 0.f) m = fmaxf(m, d[j]);
    m = fmaxf(m, __shfl_xor(m, 32));        // wave-wide max (uniform)

    float e[16];
    float ps = 0.f;
    #pragma unroll
    for (int j = 0; j < 16; ++j) {
        e[j] = (mk[j] != 0.f) ? __expf(d[j] - m) : 0.f;
        ps += e[j];
    }
    ps += __shfl_xor(ps, 32);               // wave-wide sum
    if (lane == 0)
        pbuf[(size_t)b * SUBCH + subchunk] = make_float2(m, ps);

    // ---- weighted sum over staged hv
    float4 acc = make_float4(0.f, 0.f, 0.f, 0.f);
    #pragma unroll
    for (int j = 0; j < 16; ++j) {
        acc.x += e[j] * vv[j].x;
        acc.y += e[j] * vv[j].y;
        acc.z += e[j] * vv[j].z;
        acc.w += e[j] * vv[j].w;
    }
    acc.x += __shfl_xor(acc.x, 32);
    acc.y += __shfl_xor(acc.y, 32);
    acc.z += __shfl_xor(acc.z, 32);
    acc.w += __shfl_xor(acc.w, 32);
    if (p == 0)
        *(float4*)(ws_c + ((size_t)b * SUBCH + subchunk) * OO + q * 4) = acc;
}

// ---------------- K3: combine 64 flash partials (global renorm) -> c, MLP head.
__global__ __launch_bounds__(256) void final_kernel(
    const float* __restrict__ ws_c, const float2* __restrict__ pbuf,
    const float* __restrict__ sh_in,
    const float* __restrict__ W1, const float* __restrict__ b1,
    const float* __restrict__ W2, const float* __restrict__ b2,
    const float* __restrict__ W3, const float* __restrict__ b3,
    float* __restrict__ out_p, float* __restrict__ out_c)
{
    const int b = blockIdx.x, tid = threadIdx.x;
    __shared__ float marr[SUBCH], Sarr[SUBCH], fac[SUBCH];
    __shared__ float cbuf[128], shbuf[128], h1[LL], zz[LL], red2[2];

    if (tid < SUBCH) {
        float2 p = pbuf[(size_t)b * SUBCH + tid];
        marr[tid] = p.x;
        Sarr[tid] = p.y;
    }
    __syncthreads();
    if (tid < SUBCH) {
        float M = marr[0];
        #pragma unroll
        for (int i = 1; i < SUBCH; ++i) M = fmaxf(M, marr[i]);
        float S = 0.f;
        #pragma unroll
        for (int i = 0; i < SUBCH; ++i) S += Sarr[i] * __expf(marr[i] - M);
        fac[tid] = __expf(marr[tid] - M) / S;   // 0 for dead sub-chunk (marr=-inf)
    }
    __syncthreads();

    if (tid < 128) {
        float s = 0.f;
        const float* base = ws_c + (size_t)b * SUBCH * OO + tid;
        #pragma unroll 8
        for (int i = 0; i < SUBCH; ++i) s += fac[i] * base[i * OO];
        cbuf[tid] = s;
        out_c[b * OO + tid] = s;
        shbuf[tid] = sh_in[b * OO + tid];
    }
    __syncthreads();

    const int o = tid >> 2, l2 = tid & 3;
    if (o < LL) {
        float a = 0.f;
        const float* w1r = W1 + o * OO;
        const float* w2r = W2 + o * OO;
        #pragma unroll 8
        for (int j = 0; j < 32; ++j) {
            int k = l2 + 4 * j;
            a += w1r[k] * shbuf[k] + w2r[k] * cbuf[k];
        }
        a += __shfl_xor(a, 1);
        a += __shfl_xor(a, 2);
        if (l2 == 0) h1[o] = fmaxf(a + b1[o] + b2[o], 0.f);
    }
    __syncthreads();

    if (o < LL) {
        float z = 0.f;
        const float* w3r = W3 + o * LL;
        for (int j = 0; j < 9; ++j) {
            int k = l2 + 4 * j;
            if (k < LL) z += w3r[k] * h1[k];
        }
        z += __shfl_xor(z, 1);
        z += __shfl_xor(z, 2);
        if (l2 == 0) zz[o] = z + b3[o];
    }
    __syncthreads();
    if (tid == 0) {
        float mm = zz[0];
        for (int i = 1; i < LL; i++) mm = fmaxf(mm, zz[i]);
        float ss = 0.f;
        for (int i = 0; i < LL; i++) ss += __expf(zz[i] - mm);
        red2[0] = mm; red2[1] = ss;
    }
    __syncthreads();
    if (tid < LL) out_p[b * LL + tid] = __expf(zz[tid] - red2[0]) / red2[1];
}

extern "C" void kernel_launch(void* const* d_in, const int* in_sizes, int n_in,
                              void* d_out, int out_size, void* d_ws, size_t ws_size,
                              hipStream_t stream) {
    (void)in_sizes; (void)n_in; (void)out_size; (void)ws_size;
    const float* hk   = (const float*)d_in[0];
    const float* hv   = (const float*)d_in[1];
    const float* y1   = (const float*)d_in[2];
    const float* c1   = (const float*)d_in[3];
    const float* sh1  = (const float*)d_in[4];
    const float* sc1  = (const float*)d_in[5];
    const float* mask = (const float*)d_in[6];
    const float* Wih  = (const float*)d_in[7];
    const float* bih  = (const float*)d_in[8];
    const float* Whh  = (const float*)d_in[9];
    const float* bhh  = (const float*)d_in[10];
    const float* W1   = (const float*)d_in[11];
    const float* b1   = (const float*)d_in[12];
    const float* W2   = (const float*)d_in[13];
    const float* b2   = (const float*)d_in[14];
    const float* W3   = (const float*)d_in[15];
    const float* b3   = (const float*)d_in[16];

    float* out    = (float*)d_out;        // [B, L]
    float* out_c  = out + BB * LL;        // [B, O]
    float* out_sh = out_c + BB * OO;      // [B, O]
    float* out_sc = out_sh + BB * OO;     // [B, O]

    float*  ws_c = (float*)d_ws;                                // [B, SUBCH, O] (4 MB)
    float2* pbuf = (float2*)(ws_c + (size_t)BB * SUBCH * OO);   // [B, SUBCH] (m,S) 64 KB

    lstm_kernel<<<dim3(8, 32), 256, 0, stream>>>(y1, c1, sh1, sc1, Wih, bih, Whh, bhh,
                                                 out_sh, out_sc);
    attn_kernel<<<dim3(SUBCH / 4, BB), 256, 0, stream>>>(hk, hv, mask, out_sc, ws_c, pbuf);
    final_kernel<<<BB, 256, 0, stream>>>(ws_c, pbuf, out_sh, W1, b1, W2, b2, W3, b3,
                                         out, out_c);
}

// Round 4
// 331.369 us; speedup vs baseline: 1.0194x; 1.0194x over previous
//
#include <hip/hip_runtime.h>
#include <math.h>

#define BB 128
#define TT 2048
#define OO 128
#define EE 512
#define LL 34
#define XDIM 640       // O+E
#define SUBCH 64       // flash partials per batch row
#define SUB_LEN 32     // rows per wave-tile
#define NT 4           // tiles per wave

__device__ __forceinline__ float sigmoidf_(float x) { return 1.0f / (1.0f + __expf(-x)); }

// ---------------- K1: LSTM cell, fused GEMM + activation.
__global__ __launch_bounds__(256) void lstm_kernel(
    const float* __restrict__ y1, const float* __restrict__ c1,
    const float* __restrict__ sh1, const float* __restrict__ sc1,
    const float* __restrict__ Wih, const float* __restrict__ bih,
    const float* __restrict__ Whh, const float* __restrict__ bhh,
    float* __restrict__ out_sh, float* __restrict__ out_sc)
{
    __shared__ float xs[4][768];          // per batch row: [y1(512)|c1(128)|sh1(128)]
    __shared__ float gbuf[4][4][16];      // [gate][bi][o_local]
    const int tid = threadIdx.x;
    const int otile = blockIdx.x;
    const int qb = blockIdx.y * 4;

    for (int idx = tid; idx < 4 * 768; idx += 256) {
        int bi = idx / 768, k = idx - bi * 768;
        int b = qb + bi;
        float v;
        if (k < 512)      v = y1[b * EE + k];
        else if (k < 640) v = c1[b * OO + (k - 512)];
        else              v = sh1[b * OO + (k - 640)];
        xs[bi][k] = v;
    }
    __syncthreads();

    const int g = tid >> 6, l = tid & 63;   // wave g = gate g
    #pragma unroll 2
    for (int i = 0; i < 16; ++i) {
        const int row = g * 128 + otile * 16 + i;
        const float* wr = Wih + (size_t)row * XDIM;
        float a0 = 0.f, a1 = 0.f, a2 = 0.f, a3 = 0.f;
        #pragma unroll
        for (int j = 0; j < 10; ++j) {
            float wv = wr[l + 64 * j];
            a0 += wv * xs[0][l + 64 * j];
            a1 += wv * xs[1][l + 64 * j];
            a2 += wv * xs[2][l + 64 * j];
            a3 += wv * xs[3][l + 64 * j];
        }
        const float* wh = Whh + (size_t)row * OO;
        #pragma unroll
        for (int j = 0; j < 2; ++j) {
            float wv = wh[l + 64 * j];
            a0 += wv * xs[0][640 + l + 64 * j];
            a1 += wv * xs[1][640 + l + 64 * j];
            a2 += wv * xs[2][640 + l + 64 * j];
            a3 += wv * xs[3][640 + l + 64 * j];
        }
        #pragma unroll
        for (int off = 32; off >= 1; off >>= 1) {
            a0 += __shfl_xor(a0, off);
            a1 += __shfl_xor(a1, off);
            a2 += __shfl_xor(a2, off);
            a3 += __shfl_xor(a3, off);
        }
        if (l == 0) {
            float bb = bih[row] + bhh[row];
            gbuf[g][0][i] = a0 + bb;
            gbuf[g][1][i] = a1 + bb;
            gbuf[g][2][i] = a2 + bb;
            gbuf[g][3][i] = a3 + bb;
        }
    }
    __syncthreads();

    if (tid < 64) {
        const int bi = tid >> 4, ol = tid & 15;
        const int b = qb + bi, o = otile * 16 + ol;
        float gi = gbuf[0][bi][ol], gf = gbuf[1][bi][ol];
        float gg = gbuf[2][bi][ol], go = gbuf[3][bi][ol];
        float sc = sigmoidf_(gf) * sc1[b * OO + o] + sigmoidf_(gi) * tanhf(gg);
        float sh = sigmoidf_(go) * tanhf(sc);
        out_sc[b * OO + o] = sc;
        out_sh[b * OO + o] = sh;
    }
}

// ---------------- K2: tile-looping software-pipelined flash attention.
// Each wave owns NT=4 sub-chunks of 32 rows. Per iteration:
//   issue V(t)+mask(t)  ->  dot from K(t) (in flight since prev iter)
//   -> issue K(t+1)     ->  80-op shuffle reduce runs with 32KB of loads in flight
//   -> exp/weights      ->  weighted sum consumes V(t) -> store partial.
// sched_barrier(0) pins the issue points so the scheduler cannot sink the
// prefetches back to their uses (what killed rounds 2/3: VGPR 36/56).
// VMEM in-order retirement => waiting on K never drains the younger V/K(t+1).
__global__ __launch_bounds__(256, 2) void attn_kernel(
    const float* __restrict__ hk, const float* __restrict__ hv,
    const float* __restrict__ mask, const float* __restrict__ sc,
    float* __restrict__ ws_c, float2* __restrict__ pbuf)
{
    const int b = blockIdx.y;
    const int tid = threadIdx.x;
    const int wave = tid >> 6, lane = tid & 63;
    const int p = lane >> 5, q = lane & 31;    // row parity, col quad

    const float4 scq = *(const float4*)(sc + b * OO + q * 4);

    const int sc0 = blockIdx.x * (NT * 4) + wave;      // subchunk for t=0 (stride 4 per tile)
    const size_t row0 = (size_t)b * TT + sc0 * SUB_LEN;
    const float* kb = hk + (row0 + p) * OO + q * 4;
    const float* vb = hv + (row0 + p) * OO + q * 4;
    const float* mb = mask + row0;
    const size_t adv = (size_t)4 * SUB_LEN * OO;        // 4 subchunks of rows per tile step

    float4 K[16], V[16];

    // prologue: K(0) in flight
    #pragma unroll
    for (int j = 0; j < 16; ++j)
        K[j] = *(const float4*)(kb + (size_t)(2 * j) * OO);
    __builtin_amdgcn_sched_barrier(0);

    for (int t = 0; t < NT; ++t) {
        const size_t toff = (size_t)t * adv;

        // ---- issue V(t) + mask(t): younger than K(t), older than K(t+1)
        const float* vbt = vb + toff;
        #pragma unroll
        for (int j = 0; j < 16; ++j)
            V[j] = *(const float4*)(vbt + (size_t)(2 * j) * OO);
        float mval = mb[t * (4 * SUB_LEN) + (lane & 31)];
        __builtin_amdgcn_sched_barrier(0);

        // ---- dot from K(t): waits only K (oldest outstanding)
        float d[16];
        #pragma unroll
        for (int j = 0; j < 16; ++j)
            d[j] = K[j].x * scq.x + K[j].y * scq.y + K[j].z * scq.z + K[j].w * scq.w;
        __builtin_amdgcn_sched_barrier(0);

        // ---- issue K(t+1) into the same registers (K(t) fully consumed)
        if (t + 1 < NT) {
            const float* kbt = kb + toff + adv;
            #pragma unroll
            for (int j = 0; j < 16; ++j)
                K[j] = *(const float4*)(kbt + (size_t)(2 * j) * OO);
        }
        __builtin_amdgcn_sched_barrier(0);

        // ---- softmax reduce (DS pipe only; V + K(t+1) stay in flight under it)
        #pragma unroll
        for (int j = 0; j < 16; ++j) {
            d[j] += __shfl_xor(d[j], 1);
            d[j] += __shfl_xor(d[j], 2);
            d[j] += __shfl_xor(d[j], 4);
            d[j] += __shfl_xor(d[j], 8);
            d[j] += __shfl_xor(d[j], 16);
        }
        // masks for my parity's rows via shuffle of the single mask load
        float mk[16];
        #pragma unroll
        for (int j = 0; j < 16; ++j) mk[j] = __shfl(mval, 2 * j + p);

        float m = -INFINITY;
        #pragma unroll
        for (int j = 0; j < 16; ++j) if (mk[j] != 0.f) m = fmaxf(m, d[j]);
        m = fmaxf(m, __shfl_xor(m, 32));        // wave-wide max (uniform)

        float ps = 0.f;
        #pragma unroll
        for (int j = 0; j < 16; ++j) {
            d[j] = (mk[j] != 0.f) ? __expf(d[j] - m) : 0.f;   // d becomes e (in place)
            ps += d[j];
        }
        ps += __shfl_xor(ps, 32);               // wave-wide sum

        const int subchunk = sc0 + t * 4;
        if (lane == 0)
            pbuf[(size_t)b * SUBCH + subchunk] = make_float2(m, ps);

        // ---- weighted sum over V(t) (wait drains V; K(t+1) stays outstanding)
        float4 acc = make_float4(0.f, 0.f, 0.f, 0.f);
        #pragma unroll
        for (int j = 0; j < 16; ++j) {
            acc.x += d[j] * V[j].x;
            acc.y += d[j] * V[j].y;
            acc.z += d[j] * V[j].z;
            acc.w += d[j] * V[j].w;
        }
        acc.x += __shfl_xor(acc.x, 32);
        acc.y += __shfl_xor(acc.y, 32);
        acc.z += __shfl_xor(acc.z, 32);
        acc.w += __shfl_xor(acc.w, 32);
        if (p == 0)
            *(float4*)(ws_c + ((size_t)b * SUBCH + subchunk) * OO + q * 4) = acc;
        __builtin_amdgcn_sched_barrier(0);
    }
}

// ---------------- K3: combine 64 flash partials (global renorm) -> c, MLP head.
__global__ __launch_bounds__(256) void final_kernel(
    const float* __restrict__ ws_c, const float2* __restrict__ pbuf,
    const float* __restrict__ sh_in,
    const float* __restrict__ W1, const float* __restrict__ b1,
    const float* __restrict__ W2, const float* __restrict__ b2,
    const float* __restrict__ W3, const float* __restrict__ b3,
    float* __restrict__ out_p, float* __restrict__ out_c)
{
    const int b = blockIdx.x, tid = threadIdx.x;
    __shared__ float marr[SUBCH], Sarr[SUBCH], fac[SUBCH];
    __shared__ float cbuf[128], shbuf[128], h1[LL], zz[LL], red2[2];

    if (tid < SUBCH) {
        float2 p = pbuf[(size_t)b * SUBCH + tid];
        marr[tid] = p.x;
        Sarr[tid] = p.y;
    }
    __syncthreads();
    if (tid < SUBCH) {
        float M = marr[0];
        #pragma unroll
        for (int i = 1; i < SUBCH; ++i) M = fmaxf(M, marr[i]);
        float S = 0.f;
        #pragma unroll
        for (int i = 0; i < SUBCH; ++i) S += Sarr[i] * __expf(marr[i] - M);
        fac[tid] = __expf(marr[tid] - M) / S;   // 0 for dead sub-chunk (marr=-inf)
    }
    __syncthreads();

    if (tid < 128) {
        float s = 0.f;
        const float* base = ws_c + (size_t)b * SUBCH * OO + tid;
        #pragma unroll 8
        for (int i = 0; i < SUBCH; ++i) s += fac[i] * base[i * OO];
        cbuf[tid] = s;
        out_c[b * OO + tid] = s;
        shbuf[tid] = sh_in[b * OO + tid];
    }
    __syncthreads();

    const int o = tid >> 2, l2 = tid & 3;
    if (o < LL) {
        float a = 0.f;
        const float* w1r = W1 + o * OO;
        const float* w2r = W2 + o * OO;
        #pragma unroll 8
        for (int j = 0; j < 32; ++j) {
            int k = l2 + 4 * j;
            a += w1r[k] * shbuf[k] + w2r[k] * cbuf[k];
        }
        a += __shfl_xor(a, 1);
        a += __shfl_xor(a, 2);
        if (l2 == 0) h1[o] = fmaxf(a + b1[o] + b2[o], 0.f);
    }
    __syncthreads();

    if (o < LL) {
        float z = 0.f;
        const float* w3r = W3 + o * LL;
        for (int j = 0; j < 9; ++j) {
            int k = l2 + 4 * j;
            if (k < LL) z += w3r[k] * h1[k];
        }
        z += __shfl_xor(z, 1);
        z += __shfl_xor(z, 2);
        if (l2 == 0) zz[o] = z + b3[o];
    }
    __syncthreads();
    if (tid == 0) {
        float mm = zz[0];
        for (int i = 1; i < LL; i++) mm = fmaxf(mm, zz[i]);
        float ss = 0.f;
        for (int i = 0; i < LL; i++) ss += __expf(zz[i] - mm);
        red2[0] = mm; red2[1] = ss;
    }
    __syncthreads();
    if (tid < LL) out_p[b * LL + tid] = __expf(zz[tid] - red2[0]) / red2[1];
}

extern "C" void kernel_launch(void* const* d_in, const int* in_sizes, int n_in,
                              void* d_out, int out_size, void* d_ws, size_t ws_size,
                              hipStream_t stream) {
    (void)in_sizes; (void)n_in; (void)out_size; (void)ws_size;
    const float* hk   = (const float*)d_in[0];
    const float* hv   = (const float*)d_in[1];
    const float* y1   = (const float*)d_in[2];
    const float* c1   = (const float*)d_in[3];
    const float* sh1  = (const float*)d_in[4];
    const float* sc1  = (const float*)d_in[5];
    const float* mask = (const float*)d_in[6];
    const float* Wih  = (const float*)d_in[7];
    const float* bih  = (const float*)d_in[8];
    const float* Whh  = (const float*)d_in[9];
    const float* bhh  = (const float*)d_in[10];
    const float* W1   = (const float*)d_in[11];
    const float* b1   = (const float*)d_in[12];
    const float* W2   = (const float*)d_in[13];
    const float* b2   = (const float*)d_in[14];
    const float* W3   = (const float*)d_in[15];
    const float* b3   = (const float*)d_in[16];

    float* out    = (float*)d_out;        // [B, L]
    float* out_c  = out + BB * LL;        // [B, O]
    float* out_sh = out_c + BB * OO;      // [B, O]
    float* out_sc = out_sh + BB * OO;     // [B, O]

    float*  ws_c = (float*)d_ws;                                // [B, SUBCH, O] (4 MB)
    float2* pbuf = (float2*)(ws_c + (size_t)BB * SUBCH * OO);   // [B, SUBCH] (m,S) 64 KB

    lstm_kernel<<<dim3(8, 32), 256, 0, stream>>>(y1, c1, sh1, sc1, Wih, bih, Whh, bhh,
                                                 out_sh, out_sc);
    // 4 blocks/row x 128 rows = 512 blocks; 4 waves/block; 4 tiles/wave.
    attn_kernel<<<dim3(SUBCH / (4 * NT), BB), 256, 0, stream>>>(hk, hv, mask, out_sc,
                                                                ws_c, pbuf);
    final_kernel<<<BB, 256, 0, stream>>>(ws_c, pbuf, out_sh, W1, b1, W2, b2, W3, b3,
                                         out, out_c);
}

// Round 5
// 320.016 us; speedup vs baseline: 1.0556x; 1.0355x over previous
//
#include <hip/hip_runtime.h>
#include <math.h>

#define BB 128
#define TT 2048
#define OO 128
#define EE 512
#define LL 34
#define XDIM 640       // O+E
#define SUBCH 64       // flash partials per batch row
#define SUB_LEN 32     // rows per wave

typedef float f4 __attribute__((ext_vector_type(4)));

__device__ __forceinline__ float sigmoidf_(float x) { return 1.0f / (1.0f + __expf(-x)); }
// non-temporal 16B load: no-allocate in the cache hierarchy (MUBUF nt).
__device__ __forceinline__ f4 ntld(const float* p) {
    return __builtin_nontemporal_load((const f4*)p);
}

// ---------------- K1: LSTM cell, fused GEMM + activation.
__global__ __launch_bounds__(256) void lstm_kernel(
    const float* __restrict__ y1, const float* __restrict__ c1,
    const float* __restrict__ sh1, const float* __restrict__ sc1,
    const float* __restrict__ Wih, const float* __restrict__ bih,
    const float* __restrict__ Whh, const float* __restrict__ bhh,
    float* __restrict__ out_sh, float* __restrict__ out_sc)
{
    __shared__ float xs[4][768];          // per batch row: [y1(512)|c1(128)|sh1(128)]
    __shared__ float gbuf[4][4][16];      // [gate][bi][o_local]
    const int tid = threadIdx.x;
    const int otile = blockIdx.x;
    const int qb = blockIdx.y * 4;

    for (int idx = tid; idx < 4 * 768; idx += 256) {
        int bi = idx / 768, k = idx - bi * 768;
        int b = qb + bi;
        float v;
        if (k < 512)      v = y1[b * EE + k];
        else if (k < 640) v = c1[b * OO + (k - 512)];
        else              v = sh1[b * OO + (k - 640)];
        xs[bi][k] = v;
    }
    __syncthreads();

    const int g = tid >> 6, l = tid & 63;   // wave g = gate g
    #pragma unroll 2
    for (int i = 0; i < 16; ++i) {
        const int row = g * 128 + otile * 16 + i;
        const float* wr = Wih + (size_t)row * XDIM;
        float a0 = 0.f, a1 = 0.f, a2 = 0.f, a3 = 0.f;
        #pragma unroll
        for (int j = 0; j < 10; ++j) {
            float wv = wr[l + 64 * j];
            a0 += wv * xs[0][l + 64 * j];
            a1 += wv * xs[1][l + 64 * j];
            a2 += wv * xs[2][l + 64 * j];
            a3 += wv * xs[3][l + 64 * j];
        }
        const float* wh = Whh + (size_t)row * OO;
        #pragma unroll
        for (int j = 0; j < 2; ++j) {
            float wv = wh[l + 64 * j];
            a0 += wv * xs[0][640 + l + 64 * j];
            a1 += wv * xs[1][640 + l + 64 * j];
            a2 += wv * xs[2][640 + l + 64 * j];
            a3 += wv * xs[3][640 + l + 64 * j];
        }
        #pragma unroll
        for (int off = 32; off >= 1; off >>= 1) {
            a0 += __shfl_xor(a0, off);
            a1 += __shfl_xor(a1, off);
            a2 += __shfl_xor(a2, off);
            a3 += __shfl_xor(a3, off);
        }
        if (l == 0) {
            float bb = bih[row] + bhh[row];
            gbuf[g][0][i] = a0 + bb;
            gbuf[g][1][i] = a1 + bb;
            gbuf[g][2][i] = a2 + bb;
            gbuf[g][3][i] = a3 + bb;
        }
    }
    __syncthreads();

    if (tid < 64) {
        const int bi = tid >> 4, ol = tid & 15;
        const int b = qb + bi, o = otile * 16 + ol;
        float gi = gbuf[0][bi][ol], gf = gbuf[1][bi][ol];
        float gg = gbuf[2][bi][ol], go = gbuf[3][bi][ol];
        float sc = sigmoidf_(gf) * sc1[b * OO + o] + sigmoidf_(gi) * tanhf(gg);
        float sh = sigmoidf_(go) * tanhf(sc);
        out_sc[b * OO + o] = sc;
        out_sh[b * OO + o] = sh;
    }
}

// ---------------- K2: barrier-free flash attention partials.
// Round-2 structure (best measured) + two changes:
//  (1) dead-tile skip: one 128B mask load + __ballot per wave; fully-masked
//      32-row sub-chunks (~24% of all tiles) fetch ZERO hk/hv bytes.
//  (2) non-temporal hk/hv loads: no-allocate -> the 268MB stream stops
//      thrashing the 256MB LLC (hypothesis: TCC allocate/evict churn is the
//      ~2.8 TB/s delivered-BW cap; fill's write path does 6.9 TB/s).
__global__ __launch_bounds__(256) void attn_kernel(
    const float* __restrict__ hk, const float* __restrict__ hv,
    const float* __restrict__ mask, const float* __restrict__ sc,
    float* __restrict__ ws_c, float2* __restrict__ pbuf)
{
    const int b = blockIdx.y;
    const int tid = threadIdx.x;
    const int wave = tid >> 6, lane = tid & 63;
    const int subchunk = blockIdx.x * 4 + wave;     // 0..63
    const int sg = (lane >> 4) & 3, l = lane & 15;  // 4 subgroups x 16 lanes
    const int r0 = subchunk * SUB_LEN;

    // one coalesced mask load per wave (lanes 32-63 duplicate lanes 0-31)
    const float mval = mask[(size_t)b * TT + r0 + (lane & 31)];
    const unsigned long long bal = __ballot(mval != 0.f);   // bits 0..31 = row validity

    if (bal == 0ull) {
        // fully-dead sub-chunk: no hk/hv traffic. ws_c MUST be zeroed
        // (workspace is poisoned; final kernel computes fac*ws_c and 0*NaN=NaN).
        if (lane == 0)
            pbuf[(size_t)b * SUBCH + subchunk] = make_float2(-INFINITY, 0.f);
        if (lane < 32)
            *(float4*)(ws_c + ((size_t)b * SUBCH + subchunk) * OO + lane * 4) =
                make_float4(0.f, 0.f, 0.f, 0.f);
        return;
    }

    // ---- scores: each subgroup handles 8 rows; 32B/lane/row from hk.
    const float4 scA = *(const float4*)(sc + b * OO + l * 8);
    const float4 scB = *(const float4*)(sc + b * OO + l * 8 + 4);
    const float* krow = hk + ((size_t)b * TT + r0 + sg * 8) * OO;

    float s[8];
    #pragma unroll
    for (int i = 0; i < 8; ++i) {
        f4 a  = ntld(krow + (size_t)i * OO + l * 8);
        f4 c2 = ntld(krow + (size_t)i * OO + l * 8 + 4);
        s[i] = a.x * scA.x + a.y * scA.y + a.z * scA.z + a.w * scA.w
             + c2.x * scB.x + c2.y * scB.y + c2.z * scB.z + c2.w * scB.w;
    }
    #pragma unroll
    for (int i = 0; i < 8; ++i) {
        s[i] += __shfl_xor(s[i], 8);
        s[i] += __shfl_xor(s[i], 4);
        s[i] += __shfl_xor(s[i], 2);
        s[i] += __shfl_xor(s[i], 1);
    }
    float m = -INFINITY;
    #pragma unroll
    for (int i = 0; i < 8; ++i)
        if ((bal >> (sg * 8 + i)) & 1ull) m = fmaxf(m, s[i]);
    m = fmaxf(m, __shfl_xor(m, 16));
    m = fmaxf(m, __shfl_xor(m, 32));        // wave-wide max (uniform)

    float e[8];
    float ps = 0.f;
    #pragma unroll
    for (int i = 0; i < 8; ++i) {
        e[i] = ((bal >> (sg * 8 + i)) & 1ull) ? __expf(s[i] - m) : 0.f;
        ps += e[i];
    }
    ps += __shfl_xor(ps, 16);
    ps += __shfl_xor(ps, 32);               // wave-wide sum (uniform)
    if (lane == 0)
        pbuf[(size_t)b * SUBCH + subchunk] = make_float2(m, ps);

    // ---- weighted sum over hv: lane covers 4 cols, 2 row-interleave groups.
    const int c4 = (lane & 31) * 4, rp = lane >> 5;
    float4 acc = make_float4(0.f, 0.f, 0.f, 0.f);
    const float* vbase = hv + ((size_t)b * TT + r0) * OO + c4;
    #pragma unroll
    for (int sgi = 0; sgi < 4; ++sgi) {
        float wv[8];
        #pragma unroll
        for (int i = 0; i < 8; ++i) wv[i] = __shfl(e[i], sgi * 16);
        #pragma unroll
        for (int j = 0; j < 4; ++j) {
            const int row = sgi * 8 + j * 2 + rp;
            f4 v = ntld(vbase + (size_t)row * OO);
            float w = (rp == 0) ? wv[2 * j] : wv[2 * j + 1];  // static idx + cndmask
            acc.x += w * v.x;
            acc.y += w * v.y;
            acc.z += w * v.z;
            acc.w += w * v.w;
        }
    }
    acc.x += __shfl_xor(acc.x, 32);
    acc.y += __shfl_xor(acc.y, 32);
    acc.z += __shfl_xor(acc.z, 32);
    acc.w += __shfl_xor(acc.w, 32);
    if (rp == 0)
        *(float4*)(ws_c + ((size_t)b * SUBCH + subchunk) * OO + c4) = acc;
}

// ---------------- K3: combine 64 flash partials (global renorm) -> c, MLP head.
__global__ __launch_bounds__(256) void final_kernel(
    const float* __restrict__ ws_c, const float2* __restrict__ pbuf,
    const float* __restrict__ sh_in,
    const float* __restrict__ W1, const float* __restrict__ b1,
    const float* __restrict__ W2, const float* __restrict__ b2,
    const float* __restrict__ W3, const float* __restrict__ b3,
    float* __restrict__ out_p, float* __restrict__ out_c)
{
    const int b = blockIdx.x, tid = threadIdx.x;
    __shared__ float marr[SUBCH], Sarr[SUBCH], fac[SUBCH];
    __shared__ float cbuf[128], shbuf[128], h1[LL], zz[LL], red2[2];

    if (tid < SUBCH) {
        float2 p = pbuf[(size_t)b * SUBCH + tid];
        marr[tid] = p.x;
        Sarr[tid] = p.y;
    }
    __syncthreads();
    if (tid < SUBCH) {
        float M = marr[0];
        #pragma unroll
        for (int i = 1; i < SUBCH; ++i) M = fmaxf(M, marr[i]);
        float S = 0.f;
        #pragma unroll
        for (int i = 0; i < SUBCH; ++i) S += Sarr[i] * __expf(marr[i] - M);
        fac[tid] = __expf(marr[tid] - M) / S;   // 0 for dead sub-chunk (marr=-inf)
    }
    __syncthreads();

    if (tid < 128) {
        float s = 0.f;
        const float* base = ws_c + (size_t)b * SUBCH * OO + tid;
        #pragma unroll 8
        for (int i = 0; i < SUBCH; ++i) s += fac[i] * base[i * OO];
        cbuf[tid] = s;
        out_c[b * OO + tid] = s;
        shbuf[tid] = sh_in[b * OO + tid];
    }
    __syncthreads();

    const int o = tid >> 2, l2 = tid & 3;
    if (o < LL) {
        float a = 0.f;
        const float* w1r = W1 + o * OO;
        const float* w2r = W2 + o * OO;
        #pragma unroll 8
        for (int j = 0; j < 32; ++j) {
            int k = l2 + 4 * j;
            a += w1r[k] * shbuf[k] + w2r[k] * cbuf[k];
        }
        a += __shfl_xor(a, 1);
        a += __shfl_xor(a, 2);
        if (l2 == 0) h1[o] = fmaxf(a + b1[o] + b2[o], 0.f);
    }
    __syncthreads();

    if (o < LL) {
        float z = 0.f;
        const float* w3r = W3 + o * LL;
        for (int j = 0; j < 9; ++j) {
            int k = l2 + 4 * j;
            if (k < LL) z += w3r[k] * h1[k];
        }
        z += __shfl_xor(z, 1);
        z += __shfl_xor(z, 2);
        if (l2 == 0) zz[o] = z + b3[o];
    }
    __syncthreads();
    if (tid == 0) {
        float mm = zz[0];
        for (int i = 1; i < LL; i++) mm = fmaxf(mm, zz[i]);
        float ss = 0.f;
        for (int i = 0; i < LL; i++) ss += __expf(zz[i] - mm);
        red2[0] = mm; red2[1] = ss;
    }
    __syncthreads();
    if (tid < LL) out_p[b * LL + tid] = __expf(zz[tid] - red2[0]) / red2[1];
}

extern "C" void kernel_launch(void* const* d_in, const int* in_sizes, int n_in,
                              void* d_out, int out_size, void* d_ws, size_t ws_size,
                              hipStream_t stream) {
    (void)in_sizes; (void)n_in; (void)out_size; (void)ws_size;
    const float* hk   = (const float*)d_in[0];
    const float* hv   = (const float*)d_in[1];
    const float* y1   = (const float*)d_in[2];
    const float* c1   = (const float*)d_in[3];
    const float* sh1  = (const float*)d_in[4];
    const float* sc1  = (const float*)d_in[5];
    const float* mask = (const float*)d_in[6];
    const float* Wih  = (const float*)d_in[7];
    const float* bih  = (const float*)d_in[8];
    const float* Whh  = (const float*)d_in[9];
    const float* bhh  = (const float*)d_in[10];
    const float* W1   = (const float*)d_in[11];
    const float* b1   = (const float*)d_in[12];
    const float* W2   = (const float*)d_in[13];
    const float* b2   = (const float*)d_in[14];
    const float* W3   = (const float*)d_in[15];
    const float* b3   = (const float*)d_in[16];

    float* out    = (float*)d_out;        // [B, L]
    float* out_c  = out + BB * LL;        // [B, O]
    float* out_sh = out_c + BB * OO;      // [B, O]
    float* out_sc = out_sh + BB * OO;     // [B, O]

    float*  ws_c = (float*)d_ws;                                // [B, SUBCH, O] (4 MB)
    float2* pbuf = (float2*)(ws_c + (size_t)BB * SUBCH * OO);   // [B, SUBCH] (m,S) 64 KB

    lstm_kernel<<<dim3(8, 32), 256, 0, stream>>>(y1, c1, sh1, sc1, Wih, bih, Whh, bhh,
                                                 out_sh, out_sc);
    attn_kernel<<<dim3(SUBCH / 4, BB), 256, 0, stream>>>(hk, hv, mask, out_sc, ws_c, pbuf);
    final_kernel<<<BB, 256, 0, stream>>>(ws_c, pbuf, out_sh, W1, b1, W2, b2, W3, b3,
                                         out, out_c);
}